// Round 5
// baseline (35.386 us; speedup 1.0000x reference)
//
#include <hip/hip_runtime.h>
#include <math.h>

#define NB   64
#define D    256
#define HW   25
#define TRI  32896         // 256*257/2
#define ASTR 68            // padded p-row stride for 64-wide i-panel (floats)
#define BSTR 36            // padded p-row stride for 32-wide j-panel (floats)

// tile id t (0..9) -> band pair (bi<=bj) of 4 bands of 64 rows
__device__ __forceinline__ void tile_bands(int t, int& bi, int& bj) {
    bi = (t < 4) ? 0 : (t < 7) ? 1 : (t < 9) ? 2 : 3;
    const int o4 = (bi == 0) ? 0 : (bi == 1) ? 4 : (bi == 2) ? 7 : 9;
    bj = bi + (t - o4);
}

// blk (0..1279) -> (b, bi, bj, h): 20 half-tiles per batch (10 band pairs x 2 j-halves)
__device__ __forceinline__ void decode_blk(int blk, int& b, int& bi, int& bj, int& h) {
    b = blk / 20;
    const int rem = blk - b * 20;
    const int t = rem >> 1;
    h = rem & 1;
    tile_bands(t, bi, bj);
}

// ---------------------------------------------------------------------------
// K1: one 64(i) x 32(j) half-tile per block. 1280 blocks (= 5/CU exact),
// 128 threads = 8(tx) x 16(ty), thread owns 4x4 of
//   e(i,j) = sum_p |f_i+f_j| - |f_i-f_j|.
// Writes raw e to d_out triu layout; partial row-sum vectors to collision-free
// d_ws slots: 8 slots per (b,band):
//   i-contrib of (bi,bj,h)        -> band bi, slot (bj-bi)*2+h      (len 64)
//   j-contrib of (bi<bj, h)       -> band bj, slot (4-bj)*2+bi, half h (len 32)
//   diag (bi==bj): i-contrib only.  Band W uses slots [0, 8-W).
// ---------------------------------------------------------------------------
__global__ __launch_bounds__(128) void tile_kernel(const float* __restrict__ feat,
                                                   float* __restrict__ rsp,
                                                   float* __restrict__ out) {
    __shared__ __align__(16) float as[HW * ASTR];
    __shared__ __align__(16) float bs[HW * BSTR];
    __shared__ float red0[64][9];    // i-partials, reduce over tx (8)
    __shared__ float red1[32][17];   // j-partials, reduce over ty (16)

    const int tid = threadIdx.x;
    int b, bi, bj, h;
    decode_blk(blockIdx.x, b, bi, bj, h);
    const int ibase = bi * 64;
    const int jbase = bj * 64 + h * 32;
    const bool diag = (bi == bj);

    const float* fb = feat + (size_t)b * D * HW;

    // stage transposed, conflict-free writes (lanes sweep r/c at fixed-ish p)
    for (int idx = tid; idx < HW * 64; idx += 128) {
        const int p = idx >> 6, r = idx & 63;
        as[p * ASTR + r] = fb[(ibase + r) * HW + p];
    }
    for (int idx = tid; idx < HW * 32; idx += 128) {
        const int p = idx >> 5, c = idx & 31;
        bs[p * BSTR + c] = fb[(jbase + c) * HW + p];
    }
    __syncthreads();

    const int tx = tid & 7;
    const int ty = tid >> 3;

    float acc[4][4] = {{0.f}};
#pragma unroll
    for (int p = 0; p < HW; ++p) {
        float4 av = *reinterpret_cast<const float4*>(&as[p * ASTR + ty * 4]);
        float4 bv = *reinterpret_cast<const float4*>(&bs[p * BSTR + tx * 4]);
        float a4[4] = {av.x, av.y, av.z, av.w};
        float b4[4] = {bv.x, bv.y, bv.z, bv.w};
#pragma unroll
        for (int r = 0; r < 4; ++r)
#pragma unroll
            for (int q = 0; q < 4; ++q)
                acc[r][q] += fabsf(a4[r] + b4[q]) - fabsf(a4[r] - b4[q]);
    }

    // raw e -> d_out triu
    float* ob = out + (size_t)b * TRI;
#pragma unroll
    for (int r = 0; r < 4; ++r) {
        const int i = ibase + ty * 4 + r;
        const int rowoff = (i * (513 - i)) >> 1;
#pragma unroll
        for (int q = 0; q < 4; ++q) {
            const int j = jbase + tx * 4 + q;
            if (!diag || j >= i) ob[rowoff + (j - i)] = acc[r][q];
        }
    }

    // partial row vectors
    float pi[4], pj[4];
#pragma unroll
    for (int r = 0; r < 4; ++r) pi[r] = acc[r][0] + acc[r][1] + acc[r][2] + acc[r][3];
#pragma unroll
    for (int q = 0; q < 4; ++q) pj[q] = acc[0][q] + acc[1][q] + acc[2][q] + acc[3][q];
#pragma unroll
    for (int r = 0; r < 4; ++r) red0[ty * 4 + r][tx] = pi[r];
#pragma unroll
    for (int q = 0; q < 4; ++q) red1[tx * 4 + q][ty] = pj[q];
    __syncthreads();

    if (tid < 64) {
        float s = 0.f;
#pragma unroll
        for (int x = 0; x < 8; ++x) s += red0[tid][x];
        rsp[(((b * 4 + bi) * 8) + (bj - bi) * 2 + h) * 64 + tid] = s;
    } else if (tid < 96 && !diag) {
        const int c = tid - 64;
        float s = 0.f;
#pragma unroll
        for (int x = 0; x < 16; ++x) s += red1[c][x];
        rsp[(((b * 4 + bj) * 8) + (4 - bj) * 2 + bi) * 64 + h * 32 + c] = s;
    }
}

// ---------------------------------------------------------------------------
// K2: same grid/blockIdx mapping as K1 (same XCD -> L2-local RMW).
// Gather full row sums for the two bands (band W = sum of slots [0,8-W)),
// then in place:  out = sc*(e - (rs_i + rs_j)/256),  sc = 0.5*exp(T).
// ---------------------------------------------------------------------------
__global__ __launch_bounds__(128) void center_kernel(const float* __restrict__ temp,
                                                     const float* __restrict__ rsp,
                                                     float* __restrict__ out) {
    __shared__ float rsum0[64];
    __shared__ float rsum1[32];

    const int tid = threadIdx.x;
    int b, bi, bj, h;
    decode_blk(blockIdx.x, b, bi, bj, h);
    const int ibase = bi * 64;
    const int jbase = bj * 64 + h * 32;
    const bool diag = (bi == bj);

    if (tid < 64) {
        const int ns = 8 - bi;
        float s = 0.f;
        for (int sl = 0; sl < ns; ++sl)
            s += rsp[((b * 4 + bi) * 8 + sl) * 64 + tid];
        rsum0[tid] = s;
    } else if (tid < 96) {
        const int c = tid - 64;
        const int ns = 8 - bj;
        float s = 0.f;
        for (int sl = 0; sl < ns; ++sl)
            s += rsp[((b * 4 + bj) * 8 + sl) * 64 + h * 32 + c];
        rsum1[c] = s;
    }
    __syncthreads();

    const int tx = tid & 7;
    const int ty = tid >> 3;
    const float sc = 0.5f * expf(temp[0]);
    float* ob = out + (size_t)b * TRI;

#pragma unroll
    for (int r = 0; r < 4; ++r) {
        const int i = ibase + ty * 4 + r;
        const int rowoff = (i * (513 - i)) >> 1;
        const float ri = rsum0[ty * 4 + r];
#pragma unroll
        for (int q = 0; q < 4; ++q) {
            const int j = jbase + tx * 4 + q;
            if (!diag || j >= i) {
                float* p = &ob[rowoff + (j - i)];
                const float e = *p;
                *p = sc * (e - (ri + rsum1[tx * 4 + q]) * (1.0f / 256.0f));
            }
        }
    }
}

extern "C" void kernel_launch(void* const* d_in, const int* in_sizes, int n_in,
                              void* d_out, int out_size, void* d_ws, size_t ws_size,
                              hipStream_t stream) {
    const float* feat = (const float*)d_in[0];
    const float* temp = (const float*)d_in[1];
    float* out = (float*)d_out;
    float* rsp = (float*)d_ws;          // 64*4*8*64 floats = 512 KB slots

    tile_kernel<<<NB * 20, 128, 0, stream>>>(feat, rsp, out);
    center_kernel<<<NB * 20, 128, 0, stream>>>(temp, rsp, out);
}

// Round 6
// 28.542 us; speedup vs baseline: 1.2398x; 1.2398x over previous
//
#include <hip/hip_runtime.h>
#include <math.h>

#define NB   64
#define D    256
#define HW   25
#define TRI  32896         // 256*257/2
#define TS   64            // tile size (i and j)
#define PSTR 68            // padded p-row stride of transposed LDS (floats)

// tile id t (0..9) -> band pair (bi<=bj) of 4 bands
__device__ __forceinline__ void tile_bands(int t, int& bi, int& bj) {
    bi = (t < 4) ? 0 : (t < 7) ? 1 : (t < 9) ? 2 : 3;
    const int o4 = (bi == 0) ? 0 : (bi == 1) ? 4 : (bi == 2) ? 7 : 9;
    bj = bi + (t - o4);
}

// ---------------------------------------------------------------------------
// K1: one 64x64 triu tile per block (64 b * 10 tiles). block 256 = 16(tx:j) x
// 16(ty:i), each thread a 4x4 sub-tile of e(i,j) = sum_p |f_i+f_j|-|f_i-f_j|.
// Global reads coalesced (r-major); transposed LDS writes accept ~4-way
// conflicts (R5 lesson: the reverse trade loses much more on global reads).
// Writes raw e to d_out triu layout, and per-tile partial row-sum vectors to
// collision-free d_ws slots (band bi slot bj-bi from i-partials; band bj slot
// 4-bj+bi from j-partials; every (b,band) gets slots 0..3 exactly once).
// ---------------------------------------------------------------------------
__global__ __launch_bounds__(256) void tile_kernel(const float* __restrict__ feat,
                                                   float* __restrict__ rsp,
                                                   float* __restrict__ out) {
    __shared__ __align__(16) float as[HW * PSTR];
    __shared__ __align__(16) float bs[HW * PSTR];
    __shared__ float red[2][TS][17];

    const int tid = threadIdx.x;
    const int blk = blockIdx.x;
    const int b   = blk / 10;
    const int t   = blk - b * 10;
    int bi, bj; tile_bands(t, bi, bj);
    const int ibase = bi * TS, jbase = bj * TS;
    const bool diag = (bi == bj);

    const float* fb = feat + (size_t)b * D * HW;

    // stage tile rows, transposed: as[p*PSTR + r] = f[ibase+r][p]
    for (int idx = tid; idx < TS * HW; idx += 256) {
        int r = idx / HW;
        int p = idx - r * HW;
        as[p * PSTR + r] = fb[(ibase + r) * HW + p];
        bs[p * PSTR + r] = fb[(jbase + r) * HW + p];
    }
    __syncthreads();

    const int tx = tid & 15;
    const int ty = tid >> 4;

    float acc[4][4] = {{0.f}};
#pragma unroll 5
    for (int p = 0; p < HW; ++p) {
        float4 av = *reinterpret_cast<const float4*>(&as[p * PSTR + ty * 4]);
        float4 bv = *reinterpret_cast<const float4*>(&bs[p * PSTR + tx * 4]);
        float a4[4] = {av.x, av.y, av.z, av.w};
        float b4[4] = {bv.x, bv.y, bv.z, bv.w};
#pragma unroll
        for (int r = 0; r < 4; ++r)
#pragma unroll
            for (int q = 0; q < 4; ++q)
                acc[r][q] += fabsf(a4[r] + b4[q]) - fabsf(a4[r] - b4[q]);
    }

    // raw e -> d_out triu
    float* ob = out + (size_t)b * TRI;
    if (diag) {
#pragma unroll
        for (int r = 0; r < 4; ++r) {
            const int i = ibase + ty * 4 + r;
            const int rowoff = (i * (513 - i)) >> 1;
#pragma unroll
            for (int q = 0; q < 4; ++q) {
                const int j = jbase + tx * 4 + q;
                if (j >= i) ob[rowoff + (j - i)] = acc[r][q];
            }
        }
    } else {
#pragma unroll
        for (int r = 0; r < 4; ++r) {
            const int i = ibase + ty * 4 + r;
            const int rowoff = (i * (513 - i)) >> 1;
#pragma unroll
            for (int q = 0; q < 4; ++q) {
                const int j = jbase + tx * 4 + q;
                ob[rowoff + (j - i)] = acc[r][q];
            }
        }
    }

    // partial row vectors -> slots (j-partials only needed off-diagonal)
    float pi[4];
#pragma unroll
    for (int r = 0; r < 4; ++r) pi[r] = acc[r][0] + acc[r][1] + acc[r][2] + acc[r][3];
#pragma unroll
    for (int r = 0; r < 4; ++r) red[0][ty * 4 + r][tx] = pi[r];
    if (!diag) {
        float pj[4];
#pragma unroll
        for (int q = 0; q < 4; ++q) pj[q] = acc[0][q] + acc[1][q] + acc[2][q] + acc[3][q];
#pragma unroll
        for (int q = 0; q < 4; ++q) red[1][tx * 4 + q][ty] = pj[q];
    }
    __syncthreads();

    if (tid < TS) {
        float si = 0.f;
#pragma unroll
        for (int x = 0; x < 16; ++x) si += red[0][tid][x];
        rsp[((b * 4 + bi) * 4 + (bj - bi)) * TS + tid] = si;
        if (!diag) {
            float sj = 0.f;
#pragma unroll
            for (int x = 0; x < 16; ++x) sj += red[1][tid][x];
            rsp[((b * 4 + bj) * 4 + (4 - bj + bi)) * TS + tid] = sj;
        }
    }
}

// ---------------------------------------------------------------------------
// K2: same tile map (same-XCD L2 locality with K1's writes). Reduce the two
// bands' slot vectors to full row sums, then in-place:
//   out = sc*(e - (rs_i + rs_j)/256),  sc = 0.5*exp(T)
// ---------------------------------------------------------------------------
__global__ __launch_bounds__(256) void center_kernel(const float* __restrict__ temp,
                                                     const float* __restrict__ rsp,
                                                     float* __restrict__ out) {
    __shared__ float rsum[2][TS];

    const int tid = threadIdx.x;
    const int blk = blockIdx.x;
    const int b   = blk / 10;
    const int t   = blk - b * 10;
    int bi, bj; tile_bands(t, bi, bj);
    const int ibase = bi * TS, jbase = bj * TS;
    const bool diag = (bi == bj);

    if (tid < TS) {
        float s = 0.f;
#pragma unroll
        for (int sl = 0; sl < 4; ++sl) s += rsp[((b * 4 + bi) * 4 + sl) * TS + tid];
        rsum[0][tid] = s;
    } else if (tid < 2 * TS) {
        const int il = tid - TS;
        float s = 0.f;
#pragma unroll
        for (int sl = 0; sl < 4; ++sl) s += rsp[((b * 4 + bj) * 4 + sl) * TS + il];
        rsum[1][il] = s;
    }
    __syncthreads();

    const int tx = tid & 15;
    const int ty = tid >> 4;
    const float sc = 0.5f * expf(temp[0]);
    float* ob = out + (size_t)b * TRI;

#pragma unroll
    for (int r = 0; r < 4; ++r) {
        const int i = ibase + ty * 4 + r;
        const int rowoff = (i * (513 - i)) >> 1;
        const float ri = rsum[0][ty * 4 + r];
#pragma unroll
        for (int q = 0; q < 4; ++q) {
            const int j = jbase + tx * 4 + q;
            if (!diag || j >= i) {
                float* p = &ob[rowoff + (j - i)];
                const float e = *p;
                *p = sc * (e - (ri + rsum[1][tx * 4 + q]) * (1.0f / 256.0f));
            }
        }
    }
}

extern "C" void kernel_launch(void* const* d_in, const int* in_sizes, int n_in,
                              void* d_out, int out_size, void* d_ws, size_t ws_size,
                              hipStream_t stream) {
    const float* feat = (const float*)d_in[0];
    const float* temp = (const float*)d_in[1];
    float* out = (float*)d_out;
    float* rsp = (float*)d_ws;          // 64*4*4*64 floats = 256 KB slots

    tile_kernel<<<NB * 10, 256, 0, stream>>>(feat, rsp, out);
    center_kernel<<<NB * 10, 256, 0, stream>>>(temp, rsp, out);
}